// Round 9
// baseline (152.301 us; speedup 1.0000x reference)
//
#include <hip/hip_runtime.h>
#include <hip/hip_bf16.h>

// CapsuleLayer on MI355X — R13: R12's barrier-free ≤128-reg design, WITHOUT
// the spills. R12 post-mortem: WRITE_SIZE 170MB/FETCH 136MB = scratch spill
// traffic — demand ~160 regs vs the 128 cap forced by launch_bounds(512,4).
// Fix the register PLAN, not the cap: acc[4][2]=32, A single transient a[4]
// =32 (TLP at 4 waves/SIMD hides LDS latency; no parity dbuf), B half-kk
// parity dbuf bbuf[2][2]=32, addressing ~20 -> ~116 total. Zero mid-loop
// barriers; fragment-ordered L2-resident B; stride-68 As (0 conflicts
// measured R10-R12); ut staging (1KB-contiguous wave reads).
// b stays 0 (faithful torch bug) => one dense conv 64ci->128co, 5x5, pad 2;
// v = squash_z1(p/(8*cnt)); out [N, t1, z1, H, W].

#define CO 128

typedef __attribute__((ext_vector_type(8))) short bf16x8;
typedef __attribute__((ext_vector_type(4))) float f32x4;

// ---- fused prep:
//   blocks [0,800):    W fp32 [t0][co][z0][5][5] -> Wr2b bf16 fragment-order:
//                      oi = ((((kk*4+cg)*2+ks)*2+ni)<<9) + ((q*16+m16)<<3) + j
//                      (co = cg*32+ni*16+m16, ci = ks*32+q*8+j)
//   blocks [800,1824): u [n][ci][h][w] fp32 -> ut [n][h][w][ci] bf16
__global__ __launch_bounds__(256) void k_prep(const float* __restrict__ u,
                                              const float* __restrict__ Wsrc,
                                              ushort* __restrict__ ut,
                                              ushort* __restrict__ Wr2b) {
    __shared__ float lt[64][65];
    int b = blockIdx.x;
    int t = threadIdx.x;
    if (b < 800) {
        int idx = b * 256 + t;                  // 25*128*64 exact
        int ci = idx & 63;
        int r  = idx >> 6;
        int co = r & 127;
        int kk = r >> 7;
        int t0 = ci >> 4, z0 = ci & 15;
        __hip_bfloat16 bb = __float2bfloat16(Wsrc[((t0 * CO + co) * 16 + z0) * 25 + kk]);
        int cg = co >> 5, ni = (co >> 4) & 1, m16 = co & 15;
        int ks = ci >> 5, q = (ci >> 3) & 3, j = ci & 7;
        int oi = ((((kk * 4 + cg) * 2 + ks) * 2 + ni) << 9) + ((q * 16 + m16) << 3) + j;
        Wr2b[oi] = *(ushort*)&bb;
        return;
    }
    b -= 800;                                   // (n*128 + h)*2 + wchunk
    int wc = b & 1; int nh = b >> 1; int h = nh & 127; int n = nh >> 7;
    int w0 = wc * 64;
    int ciL = t >> 4;
    int wl  = (t & 15) * 4;
    const float* up = u + (size_t)n * (64 * 128 * 128) + h * 128 + w0;
#pragma unroll
    for (int p = 0; p < 4; ++p) {
        int ci = p * 16 + ciL;
        float4 v = *(const float4*)(up + (size_t)ci * 16384 + wl);
        lt[wl + 0][ci] = v.x;
        lt[wl + 1][ci] = v.y;
        lt[wl + 2][ci] = v.z;
        lt[wl + 3][ci] = v.w;
    }
    __syncthreads();
    ushort* op = ut + (((size_t)(n * 128 + h)) * 128 + w0) * 64;
#pragma unroll
    for (int p = 0; p < 2; ++p) {
        int item = p * 256 + t;
        int c8 = item & 7, w2 = item >> 3;
        bf16x8 vv;
#pragma unroll
        for (int j = 0; j < 8; ++j) {
            __hip_bfloat16 bb = __float2bfloat16(lt[w2][c8 * 8 + j]);
            vv[j] = *(ushort*)&bb;
        }
        *(bf16x8*)(op + (size_t)w2 * 64 + c8 * 8) = vv;
    }
}

// ---- main: grid 512 = 4(n) x 16(by: 8 rows) x 8(bx: 16 cols), 512 thr =
// 8 waves = rg2(4 h-rows each) x cg4(32 co each). acc[4][2] = 32 AGPR.
// As stride-68; ds_read offsets = base VGPR + compile-time immediates.
// ZERO mid-loop barriers. B prefetched one HALF-kk ahead (bbuf[2][2]).
__global__ __launch_bounds__(512, 4) void k_caps(const ushort* __restrict__ ut,
                                                 const ushort* __restrict__ Wr2b,
                                                 float* __restrict__ out) {
    __shared__ ushort As[240 * 68];      // 32640 B

    int tid = threadIdx.x;
    int bid = blockIdx.x;
    int bx = bid & 7, by = (bid >> 3) & 15, n = bid >> 7;
    int h0 = by * 8, w0 = bx * 16;

    int lane = tid & 63, wid = tid >> 6;
    int rg = wid >> 2;                   // h group (0..1): rows [wm4, wm4+4)
    int cg = wid & 3;                    // co group: 32 co
    int wm4  = rg * 4;
    int wn32 = cg * 32;
    int q = lane >> 4, m16 = lane & 15;

    // B fragment base: frag(kk,ks,ni) = wp + kk*8192 + (ks*2+ni)*512
    const ushort* wp = Wr2b + ((size_t)cg * 2048) + lane * 8;

    bf16x8 bbuf[2][2];                   // [half-kk parity][ni]
#define LOADB(par, kk2, ks2)                                              \
    {                                                                     \
        _Pragma("unroll") for (int ni_ = 0; ni_ < 2; ++ni_)               \
            bbuf[par][ni_] = *(const bf16x8*)(                            \
                wp + (size_t)(kk2) * 8192 + ((ks2) * 2 + ni_) * 512);     \
    }

    LOADB(0, 0, 0);                      // flies under the A staging

    // ---- A staging from ut: 1920 x 16B, 1KB-contiguous per wave pass.
    for (int i = tid; i < 1920; i += 512) {
        int p = i >> 3, c = i & 7;
        int rr = p / 20, cc = p - rr * 20;
        int hh = h0 + rr - 2, ww = w0 + cc - 2;
        bf16x8 v = {};
        if (((unsigned)hh < 128u) & ((unsigned)ww < 128u))
            v = *(const bf16x8*)(ut + (((size_t)(n * 128 + hh)) * 128 + ww) * 64 + c * 8);
        *(bf16x8*)&As[p * 68 + c * 8] = v;
    }
    __syncthreads();                     // the ONLY barrier

    // lane A base; per-(kk,mi,ks) deltas are compile-time immediates.
    const ushort* ap = As + (wm4 * 20 + m16) * 68 + q * 8;

    f32x4 acc[4][2] = {};

#pragma unroll
    for (int kk = 0; kk < 25; ++kk) {
        const int kh = kk / 5, kw = kk % 5;
#pragma unroll
        for (int ks = 0; ks < 2; ++ks) {
            const int h = kk * 2 + ks;
            // A frags for THIS half (transient; lgkmcnt wait inserted by
            // compiler before first MFMA use; TLP hides it)
            bf16x8 a[4];
#pragma unroll
            for (int mi = 0; mi < 4; ++mi)
                a[mi] = *(const bf16x8*)(ap + ((mi + kh) * 20 + kw) * 68 + ks * 32);
            // prefetch NEXT half-kk's B (one half ahead; in flight during MFMAs)
            if (h + 1 < 50) { LOADB((h + 1) & 1, (h + 1) >> 1, (h + 1) & 1); }
#pragma unroll
            for (int mi = 0; mi < 4; ++mi)
#pragma unroll
                for (int ni = 0; ni < 2; ++ni)
                    acc[mi][ni] = __builtin_amdgcn_mfma_f32_16x16x32_bf16(
                        a[mi], bbuf[h & 1][ni], acc[mi][ni], 0, 0, 0);
        }
    }
#undef LOADB

    // epilogue (R3-proven): scale 1/(8*cnt), squash over z1 (m16 lanes), store
    // D layout: row(m = image col) = q*4+reg, col(n = co) = m16
#pragma unroll
    for (int mi = 0; mi < 4; ++mi) {
        int h = h0 + wm4 + mi;
        int hlo = h - 2; if (hlo < 0) hlo = 0;
        int hhi = h + 2; if (hhi > 127) hhi = 127;
        float cnth = (float)(hhi - hlo + 1);
#pragma unroll
        for (int ni = 0; ni < 2; ++ni) {
            f32x4 cv = acc[mi][ni];
            float ov[4];
#pragma unroll
            for (int reg = 0; reg < 4; ++reg) {
                int w = w0 + q * 4 + reg;
                int wlo = w - 2; if (wlo < 0) wlo = 0;
                int whi = w + 2; if (whi > 127) whi = 127;
                float s = 1.f / (8.f * cnth * (float)(whi - wlo + 1));
                float pv = cv[reg] * s;
                float n2 = pv * pv;
                n2 += __shfl_xor(n2, 1);
                n2 += __shfl_xor(n2, 2);
                n2 += __shfl_xor(n2, 4);
                n2 += __shfl_xor(n2, 8);
                float fac = n2 / ((1.f + n2) * sqrtf(n2 + 1e-9f));
                ov[reg] = pv * fac;
            }
            int co = wn32 + ni * 16 + m16;
            *(float4*)(out + (((size_t)(n * CO + co)) << 14) + h * 128 + w0 + q * 4) =
                make_float4(ov[0], ov[1], ov[2], ov[3]);
        }
    }
}

extern "C" void kernel_launch(void* const* d_in, const int* in_sizes, int n_in,
                              void* d_out, int out_size, void* d_ws, size_t ws_size,
                              hipStream_t stream) {
    const float* u    = (const float*)d_in[0];
    const float* Wsrc = (const float*)d_in[1];
    float* out = (float*)d_out;
    ushort* Wr2b = (ushort*)d_ws;                      // 409600 B
    ushort* ut   = (ushort*)((char*)d_ws + 409600);    // 8388608 B

    k_prep<<<1824, 256, 0, stream>>>(u, Wsrc, ut, Wr2b);
    k_caps<<<512, 512, 0, stream>>>(ut, Wr2b, out);
}

// Round 10
// 140.011 us; speedup vs baseline: 1.0878x; 1.0878x over previous
//
#include <hip/hip_runtime.h>
#include <hip/hip_bf16.h>

// CapsuleLayer on MI355X — R14: m201-style PER-PHASE INTERLEAVE on the R6 base.
// 13 rounds established: all 2-phase variants (any barrier/vmcnt/buffer/wave
// config) plateau at 43-48us, MfmaUtil~21-25% == m233's 2-phase stall (24%).
// Documented escape (m196/m218): per-phase {ds_read frags || glds issue ->
// barrier -> lgkmcnt(0) -> PURE-REG MFMA cluster -> barrier}, counted vmcnt
// once per K-step, setprio around MFMA (T5 pays only with this role-split).
// Per kk: 2 phases (ks halves). Tri-buffered Bs, vmcnt(4) at kk end.
// b stays 0 (faithful torch bug) => one dense conv 64ci->128co, 5x5, pad 2;
// v = squash_z1(p/(8*cnt)); out [N, t1, z1, H, W].

#define CO 128

typedef __attribute__((ext_vector_type(8))) short bf16x8;
typedef __attribute__((ext_vector_type(4))) float f32x4;

__device__ __forceinline__ void glds16(const void* g, void* l) {
    __builtin_amdgcn_global_load_lds((const __attribute__((address_space(1))) void*)g,
                                     (__attribute__((address_space(3))) void*)l, 16, 0, 0);
}

// ---- fused prep:
//   blocks [0,800):   W fp32 [t0][co][z0][5][5] -> Wr2 bf16 [kk][co][chunk^(co&7)][8]
//   blocks [800,1824): u [n][ci][h][w] fp32 -> ut [n][h][w][ci] bf16
__global__ __launch_bounds__(256) void k_prep(const float* __restrict__ u,
                                              const float* __restrict__ Wsrc,
                                              ushort* __restrict__ ut,
                                              ushort* __restrict__ Wr2) {
    __shared__ float lt[64][65];
    int b = blockIdx.x;
    int t = threadIdx.x;
    if (b < 800) {
        int idx = b * 256 + t;                  // 25*128*64 exact
        int ci = idx & 63;
        int r  = idx >> 6;
        int co = r & 127;
        int kk = r >> 7;
        int t0 = ci >> 4, z0 = ci & 15;
        __hip_bfloat16 bb = __float2bfloat16(Wsrc[((t0 * CO + co) * 16 + z0) * 25 + kk]);
        int chunk = (ci >> 3) ^ (co & 7);       // XOR swizzle baked into Wr2
        Wr2[((kk * CO + co) << 6) + (chunk << 3) + (ci & 7)] = *(ushort*)&bb;
        return;
    }
    b -= 800;                                   // (n*128 + h)*2 + wchunk
    int wc = b & 1; int nh = b >> 1; int h = nh & 127; int n = nh >> 7;
    int w0 = wc * 64;
    int ciL = t >> 4;
    int wl  = (t & 15) * 4;
    const float* up = u + (size_t)n * (64 * 128 * 128) + h * 128 + w0;
#pragma unroll
    for (int p = 0; p < 4; ++p) {
        int ci = p * 16 + ciL;
        float4 v = *(const float4*)(up + (size_t)ci * 16384 + wl);
        lt[wl + 0][ci] = v.x;
        lt[wl + 1][ci] = v.y;
        lt[wl + 2][ci] = v.z;
        lt[wl + 3][ci] = v.w;
    }
    __syncthreads();
    ushort* op = ut + (((size_t)(n * 128 + h)) * 128 + w0) * 64;
#pragma unroll
    for (int p = 0; p < 2; ++p) {
        int item = p * 256 + t;
        int c8 = item & 7, w2 = item >> 3;
        bf16x8 vv;
#pragma unroll
        for (int j = 0; j < 8; ++j) {
            __hip_bfloat16 bb = __float2bfloat16(lt[w2][c8 * 8 + j]);
            vv[j] = *(ushort*)&bb;
        }
        *(bf16x8*)(op + (size_t)w2 * 64 + c8 * 8) = vv;
    }
}

// ---- main: grid 512 = 4(n) x 16(by: 8 rows) x 8(bx: 16 cols), 256 thr =
// 4 waves = rg2(4 h-rows) x cg2(64 co). As stride-68 (conflict-free,
// immediate ds_read offsets). Bs tri-buffered [3][128*64] dense swizzled.
// Per kk: 2 phases; per phase: reads+glds, BAR, lgkm0, SGB0, prio1,
// 16 MFMA, prio0, BAR (end-of-kk BAR preceded by counted vmcnt(4)).
__global__ __launch_bounds__(256) void k_caps(const ushort* __restrict__ ut,
                                              const ushort* __restrict__ Wr2,
                                              float* __restrict__ out) {
    __shared__ ushort As[240 * 68];       // 32640 B
    __shared__ ushort Bs[3 * 128 * 64];   // 49152 B  (total 81792 -> 2 blk/CU)

    int tid = threadIdx.x;
    int bid = blockIdx.x;
    int bx = bid & 7, by = (bid >> 3) & 15, n = bid >> 7;
    int h0 = by * 8, w0 = bx * 16;

    int lane = tid & 63, wid = tid >> 6;
    int rg = wid >> 1;                    // h group
    int cg = wid & 1;                     // co group
    int wm4  = rg * 4;
    int wn64 = cg * 64;
    int q = lane >> 4, m16 = lane & 15;
    int m7 = m16 & 7;

    // stage HALF of B(kk2) (j = half*2, half*2+1) into buffer at bufOfs
#define STAGEB_HALF(kk2, bufOfs, half)                                      \
    {                                                                       \
        _Pragma("unroll") for (int j_ = (half) * 2; j_ < (half) * 2 + 2; ++j_) { \
            int i_ = (j_ * 256 + wid * 64) * 8;                             \
            glds16(Wr2 + (size_t)(kk2) * 8192 + i_ + lane * 8,              \
                   &Bs[(bufOfs) + i_]);                                     \
        }                                                                   \
    }

    // prologue: B0 fully staged under the A staging
    STAGEB_HALF(0, 0, 0);
    STAGEB_HALF(0, 0, 1);

    // ---- A staging from ut: 1920 x 16B, 1KB-contiguous per wave pass.
    for (int i = tid; i < 1920; i += 256) {
        int p = i >> 3, c = i & 7;
        int rr = p / 20, cc = p - rr * 20;
        int hh = h0 + rr - 2, ww = w0 + cc - 2;
        bf16x8 v = {};
        if (((unsigned)hh < 128u) & ((unsigned)ww < 128u))
            v = *(const bf16x8*)(ut + (((size_t)(n * 128 + hh)) * 128 + ww) * 64 + c * 8);
        *(bf16x8*)&As[p * 68 + c * 8] = v;
    }
    __syncthreads();                      // drains A writes + B0 glds
    // B1 staged now — in flight under kk=0's phases
    STAGEB_HALF(1, 8192, 0);
    STAGEB_HALF(1, 8192, 1);

    const ushort* ap = As + (wm4 * 20 + m16) * 68 + q * 8;
    int bRow  = (wn64 + m16) << 6;
    int bsw0  = (q ^ m7) << 3;            // ks=0 chunk swizzle (lane-const)
    int bsw1  = ((4 + q) ^ m7) << 3;      // ks=1

    f32x4 acc[4][4] = {};

#pragma unroll
    for (int kk = 0; kk < 25; ++kk) {
        const int kh = kk / 5, kw = kk % 5;
        const int cur = (kk % 3) * 8192;
        const int nxt = ((kk + 2) % 3) * 8192;
#pragma unroll
        for (int ks = 0; ks < 2; ++ks) {
            // ---- phase: this half's frags (pure ds_read) + half the stage
            bf16x8 a[4], bb[4];
            const int bsw = ks ? bsw1 : bsw0;
#pragma unroll
            for (int mi = 0; mi < 4; ++mi)
                a[mi] = *(const bf16x8*)(ap + ((mi + kh) * 20 + kw) * 68 + ks * 32);
#pragma unroll
            for (int ni = 0; ni < 4; ++ni)
                bb[ni] = *(const bf16x8*)&Bs[cur + bRow + ni * 1024 + bsw];
            if (kk < 23) STAGEB_HALF(kk + 2, nxt, ks);
            __builtin_amdgcn_s_barrier();
            asm volatile("s_waitcnt lgkmcnt(0)" ::: "memory");
            __builtin_amdgcn_sched_barrier(0);   // rule 18: pin MFMA after wait
            __builtin_amdgcn_s_setprio(1);
#pragma unroll
            for (int mi = 0; mi < 4; ++mi)
#pragma unroll
                for (int ni = 0; ni < 4; ++ni)
                    acc[mi][ni] = __builtin_amdgcn_mfma_f32_16x16x32_bf16(
                        a[mi], bb[ni], acc[mi][ni], 0, 0, 0);
            __builtin_amdgcn_s_setprio(0);
            // end-of-phase barrier; at ks=1 precede with counted vmcnt
            if (ks == 0) {
                __builtin_amdgcn_s_barrier();
            } else if (kk < 23) {
                // (kk-1)-staged 4 glds retired -> B(kk+1) ready; kk's 4 in flight
                asm volatile("s_waitcnt vmcnt(4)" ::: "memory");
                __builtin_amdgcn_s_barrier();
            } else if (kk == 23) {
                asm volatile("s_waitcnt vmcnt(0)" ::: "memory");
                __builtin_amdgcn_s_barrier();
            }
            // kk==24, ks==1: fall through to epilogue (no LDS hazards)
        }
    }
#undef STAGEB_HALF

    // epilogue (R3-proven): scale 1/(8*cnt), squash over z1 (m16 lanes), store
    // D layout: row(m = image col) = q*4+reg, col(n = co) = m16
#pragma unroll
    for (int mi = 0; mi < 4; ++mi) {
        int h = h0 + wm4 + mi;
        int hlo = h - 2; if (hlo < 0) hlo = 0;
        int hhi = h + 2; if (hhi > 127) hhi = 127;
        float cnth = (float)(hhi - hlo + 1);
#pragma unroll
        for (int ni = 0; ni < 4; ++ni) {
            f32x4 cv = acc[mi][ni];
            float ov[4];
#pragma unroll
            for (int reg = 0; reg < 4; ++reg) {
                int w = w0 + q * 4 + reg;
                int wlo = w - 2; if (wlo < 0) wlo = 0;
                int whi = w + 2; if (whi > 127) whi = 127;
                float s = 1.f / (8.f * cnth * (float)(whi - wlo + 1));
                float pv = cv[reg] * s;
                float n2 = pv * pv;
                n2 += __shfl_xor(n2, 1);
                n2 += __shfl_xor(n2, 2);
                n2 += __shfl_xor(n2, 4);
                n2 += __shfl_xor(n2, 8);
                float fac = n2 / ((1.f + n2) * sqrtf(n2 + 1e-9f));
                ov[reg] = pv * fac;
            }
            int co = wn64 + ni * 16 + m16;
            *(float4*)(out + (((size_t)(n * CO + co)) << 14) + h * 128 + w0 + q * 4) =
                make_float4(ov[0], ov[1], ov[2], ov[3]);
        }
    }
}

extern "C" void kernel_launch(void* const* d_in, const int* in_sizes, int n_in,
                              void* d_out, int out_size, void* d_ws, size_t ws_size,
                              hipStream_t stream) {
    const float* u    = (const float*)d_in[0];
    const float* Wsrc = (const float*)d_in[1];
    float* out = (float*)d_out;
    ushort* Wr2 = (ushort*)d_ws;                       // 409600 B
    ushort* ut  = (ushort*)((char*)d_ws + 409600);     // 8388608 B

    k_prep<<<1824, 256, 0, stream>>>(u, Wsrc, ut, Wr2);
    k_caps<<<512, 256, 0, stream>>>(ut, Wr2, out);
}

// Round 12
// 129.196 us; speedup vs baseline: 1.1788x; 1.0837x over previous
//
#include <hip/hip_runtime.h>
#include <hip/hip_bf16.h>

// CapsuleLayer on MI355X — R15 (resubmit; prior round was a container failure,
// not a bench result): many-waves/SIMD x barrier-free x no-spill.
// Ledger: barriered variants (2-4 w/SIMD) all ~43-50us = 2.7x the binding
// LDS pipe (stall-bound); barrier-free at 2 w/SIMD latency-exposed (75us);
// forced-occupancy attempts spilled (R12/13: launch_bounds straitjacket).
// This round: small blocks (4 waves, 4h x 16w x 128co), As-only LDS 21.8KB
// -> 7 blocks/CU = 7 waves/SIMD by LDS limit, acc[4][2]=32, B per-wave from
// L2 in fragment order (4x1KB coalesced/kk, parity prefetch 1 kk ahead),
// ZERO mid-loop barriers, NO min-wave launch_bounds (natural allocation).
// Floors: LDS-A 8us, L2-B 12us, MFMA 10.7us.
// b stays 0 (faithful torch bug) => one dense conv 64ci->128co, 5x5, pad 2;
// v = squash_z1(p/(8*cnt)); out [N, t1, z1, H, W].

#define CO 128

typedef __attribute__((ext_vector_type(8))) short bf16x8;
typedef __attribute__((ext_vector_type(4))) float f32x4;

// ---- fused prep:
//   blocks [0,800):    W fp32 [t0][co][z0][5][5] -> Wr2b bf16 fragment-order:
//                      oi = ((((kk*4+cg)*2+ks)*2+ni)<<9) + ((q*16+m16)<<3) + j
//                      (co = cg*32+ni*16+m16, ci = ks*32+q*8+j)
//   blocks [800,1824): u [n][ci][h][w] fp32 -> ut [n][h][w][ci] bf16
__global__ __launch_bounds__(256) void k_prep(const float* __restrict__ u,
                                              const float* __restrict__ Wsrc,
                                              ushort* __restrict__ ut,
                                              ushort* __restrict__ Wr2b) {
    __shared__ float lt[64][65];
    int b = blockIdx.x;
    int t = threadIdx.x;
    if (b < 800) {
        int idx = b * 256 + t;                  // 25*128*64 exact
        int ci = idx & 63;
        int r  = idx >> 6;
        int co = r & 127;
        int kk = r >> 7;
        int t0 = ci >> 4, z0 = ci & 15;
        __hip_bfloat16 bb = __float2bfloat16(Wsrc[((t0 * CO + co) * 16 + z0) * 25 + kk]);
        int cg = co >> 5, ni = (co >> 4) & 1, m16 = co & 15;
        int ks = ci >> 5, q = (ci >> 3) & 3, j = ci & 7;
        int oi = ((((kk * 4 + cg) * 2 + ks) * 2 + ni) << 9) + ((q * 16 + m16) << 3) + j;
        Wr2b[oi] = *(ushort*)&bb;
        return;
    }
    b -= 800;                                   // (n*128 + h)*2 + wchunk
    int wc = b & 1; int nh = b >> 1; int h = nh & 127; int n = nh >> 7;
    int w0 = wc * 64;
    int ciL = t >> 4;
    int wl  = (t & 15) * 4;
    const float* up = u + (size_t)n * (64 * 128 * 128) + h * 128 + w0;
#pragma unroll
    for (int p = 0; p < 4; ++p) {
        int ci = p * 16 + ciL;
        float4 v = *(const float4*)(up + (size_t)ci * 16384 + wl);
        lt[wl + 0][ci] = v.x;
        lt[wl + 1][ci] = v.y;
        lt[wl + 2][ci] = v.z;
        lt[wl + 3][ci] = v.w;
    }
    __syncthreads();
    ushort* op = ut + (((size_t)(n * 128 + h)) * 128 + w0) * 64;
#pragma unroll
    for (int p = 0; p < 2; ++p) {
        int item = p * 256 + t;
        int c8 = item & 7, w2 = item >> 3;
        bf16x8 vv;
#pragma unroll
        for (int j = 0; j < 8; ++j) {
            __hip_bfloat16 bb = __float2bfloat16(lt[w2][c8 * 8 + j]);
            vv[j] = *(ushort*)&bb;
        }
        *(bf16x8*)(op + (size_t)w2 * 64 + c8 * 8) = vv;
    }
}

// ---- main: grid 1024 = 4(n) x 32(by: 4 rows) x 8(bx: 16 cols), 256 thr =
// 4 waves, cg = wid (32 co each); all waves share the 4h x 16w pixel tile.
// As[160*68] = 21.8KB -> 7 blocks/CU (28 waves, 7/SIMD). acc[4][2] = 32.
// ds_read offsets = base VGPR + compile-time immediates. ZERO mid-loop
// barriers. B: per-wave 4x1KB coalesced L2 loads, parity prefetch 1 kk ahead.
__global__ __launch_bounds__(256) void k_caps(const ushort* __restrict__ ut,
                                              const ushort* __restrict__ Wr2b,
                                              float* __restrict__ out) {
    __shared__ ushort As[160 * 68];      // 21760 B

    int tid = threadIdx.x;
    int bid = blockIdx.x;
    int bx = bid & 7, by = (bid >> 3) & 31, n = bid >> 8;
    int h0 = by * 4, w0 = bx * 16;

    int lane = tid & 63, wid = tid >> 6;
    int cg = wid;                        // co group: 32 co per wave
    int wn32 = cg * 32;
    int q = lane >> 4, m16 = lane & 15;

    // B fragment base: frag(kk,ks,ni) = wp + kk*8192 + (ks*2+ni)*512
    const ushort* wp = Wr2b + ((size_t)cg * 2048) + lane * 8;

    bf16x8 bbuf[2][4];                   // [kk parity][ks*2+ni]
#define LOADB(par, kk2)                                                   \
    {                                                                     \
        _Pragma("unroll") for (int f_ = 0; f_ < 4; ++f_)                  \
            bbuf[par][f_] = *(const bf16x8*)(                             \
                wp + (size_t)(kk2) * 8192 + f_ * 512);                    \
    }

    LOADB(0, 0);                         // flies under the A staging

    // ---- A staging from ut: 160 px (8 rows x 20 cols halo) x 8 chunks,
    // 1280 x 16B items, 5 passes, 1KB-contiguous per wave pass.
    for (int i = tid; i < 1280; i += 256) {
        int p = i >> 3, c = i & 7;
        int rr = p / 20, cc = p - rr * 20;
        int hh = h0 + rr - 2, ww = w0 + cc - 2;
        bf16x8 v = {};
        if (((unsigned)hh < 128u) & ((unsigned)ww < 128u))
            v = *(const bf16x8*)(ut + (((size_t)(n * 128 + hh)) * 128 + ww) * 64 + c * 8);
        *(bf16x8*)&As[p * 68 + c * 8] = v;
    }
    __syncthreads();                     // the ONLY barrier

    // lane A base; per-(kk,mi,ks) deltas are compile-time immediates.
    const ushort* ap = As + m16 * 68 + q * 8;

    f32x4 acc[4][2] = {};

#pragma unroll
    for (int kk = 0; kk < 25; ++kk) {
        const int kh = kk / 5, kw = kk % 5;
        // issue next kk's B loads FIRST (L2 latency hides under this kk)
        if (kk < 24) { LOADB((kk + 1) & 1, kk + 1); }
#pragma unroll
        for (int ks = 0; ks < 2; ++ks) {
            bf16x8 a[4];
#pragma unroll
            for (int mi = 0; mi < 4; ++mi)
                a[mi] = *(const bf16x8*)(ap + ((mi + kh) * 20 + kw) * 68 + ks * 32);
#pragma unroll
            for (int mi = 0; mi < 4; ++mi)
#pragma unroll
                for (int ni = 0; ni < 2; ++ni)
                    acc[mi][ni] = __builtin_amdgcn_mfma_f32_16x16x32_bf16(
                        a[mi], bbuf[kk & 1][ks * 2 + ni], acc[mi][ni], 0, 0, 0);
        }
    }
#undef LOADB

    // epilogue (R3-proven): scale 1/(8*cnt), squash over z1 (m16 lanes), store
    // D layout: row(m = image col) = q*4+reg, col(n = co) = m16
#pragma unroll
    for (int mi = 0; mi < 4; ++mi) {
        int h = h0 + mi;
        int hlo = h - 2; if (hlo < 0) hlo = 0;
        int hhi = h + 2; if (hhi > 127) hhi = 127;
        float cnth = (float)(hhi - hlo + 1);
#pragma unroll
        for (int ni = 0; ni < 2; ++ni) {
            f32x4 cv = acc[mi][ni];
            float ov[4];
#pragma unroll
            for (int reg = 0; reg < 4; ++reg) {
                int w = w0 + q * 4 + reg;
                int wlo = w - 2; if (wlo < 0) wlo = 0;
                int whi = w + 2; if (whi > 127) whi = 127;
                float s = 1.f / (8.f * cnth * (float)(whi - wlo + 1));
                float pv = cv[reg] * s;
                float n2 = pv * pv;
                n2 += __shfl_xor(n2, 1);
                n2 += __shfl_xor(n2, 2);
                n2 += __shfl_xor(n2, 4);
                n2 += __shfl_xor(n2, 8);
                float fac = n2 / ((1.f + n2) * sqrtf(n2 + 1e-9f));
                ov[reg] = pv * fac;
            }
            int co = wn32 + ni * 16 + m16;
            *(float4*)(out + (((size_t)(n * CO + co)) << 14) + h * 128 + w0 + q * 4) =
                make_float4(ov[0], ov[1], ov[2], ov[3]);
        }
    }
}

extern "C" void kernel_launch(void* const* d_in, const int* in_sizes, int n_in,
                              void* d_out, int out_size, void* d_ws, size_t ws_size,
                              hipStream_t stream) {
    const float* u    = (const float*)d_in[0];
    const float* Wsrc = (const float*)d_in[1];
    float* out = (float*)d_out;
    ushort* Wr2b = (ushort*)d_ws;                      // 409600 B
    ushort* ut   = (ushort*)((char*)d_ws + 409600);    // 8388608 B

    k_prep<<<1824, 256, 0, stream>>>(u, Wsrc, ut, Wr2b);
    k_caps<<<1024, 256, 0, stream>>>(ut, Wr2b, out);
}